// Round 2
// baseline (347.838 us; speedup 1.0000x reference)
//
#include <hip/hip_runtime.h>
#include <hip/hip_bf16.h>
#include <cstdint>
#include <cstddef>

// Problem constants (match reference)
constexpr int BB   = 4;
constexpr int NIN  = 4096;
constexpr int MM   = 16384;
constexpr int CIN  = 256;
constexpr int COUT = 128;
constexpr float EPSBN = 1e-5f;

// ---------------------------------------------------------------------------
// prep: transpose weights (Cout,Cin)->(Cin,Cout), fold BN into (s,t),
//       pack xyzin into float4 (x,y,z, x^2+y^2+z^2)
// ---------------------------------------------------------------------------
__global__ __launch_bounds__(256) void prep_kernel(
    const float* __restrict__ w1, const float* __restrict__ w2, const float* __restrict__ w3,
    const float* __restrict__ b1, const float* __restrict__ g1, const float* __restrict__ be1,
    const float* __restrict__ rm1, const float* __restrict__ rv1,
    const float* __restrict__ b2, const float* __restrict__ g2, const float* __restrict__ be2,
    const float* __restrict__ rm2, const float* __restrict__ rv2,
    const float* __restrict__ b3, const float* __restrict__ g3, const float* __restrict__ be3,
    const float* __restrict__ rm3, const float* __restrict__ rv3,
    const float* __restrict__ xyzin,
    float* __restrict__ WT1, float* __restrict__ WT2, float* __restrict__ WT3,
    float* __restrict__ st, float4* __restrict__ packed)
{
    int tid  = blockIdx.x * blockDim.x + threadIdx.x;
    int nthr = gridDim.x * blockDim.x;

    for (int i = tid; i < CIN * COUT; i += nthr)
        WT1[i] = w1[(i & 127) * CIN + (i >> 7)];
    for (int i = tid; i < COUT * COUT; i += nthr)
        WT2[i] = w2[(i & 127) * COUT + (i >> 7)];
    for (int i = tid; i < COUT * COUT; i += nthr)
        WT3[i] = w3[(i & 127) * COUT + (i >> 7)];

    for (int i = tid; i < 3 * COUT; i += nthr) {
        int l = i >> 7, o = i & 127;
        const float* bb = (l == 0) ? b1 : (l == 1) ? b2 : b3;
        const float* gg = (l == 0) ? g1 : (l == 1) ? g2 : g3;
        const float* be = (l == 0) ? be1 : (l == 1) ? be2 : be3;
        const float* rm = (l == 0) ? rm1 : (l == 1) ? rm2 : rm3;
        const float* rv = (l == 0) ? rv1 : (l == 1) ? rv2 : rv3;
        float s = gg[o] / sqrtf(rv[o] + EPSBN);
        st[l * 256 + o]       = s;
        st[l * 256 + 128 + o] = s * (bb[o] - rm[o]) + be[o];
    }

    for (int i = tid; i < BB * NIN; i += nthr) {
        float x = xyzin[i * 3 + 0], y = xyzin[i * 3 + 1], z = xyzin[i * 3 + 2];
        float sn = __fadd_rn(__fadd_rn(__fmul_rn(x, x), __fmul_rn(y, y)), __fmul_rn(z, z));
        packed[i] = make_float4(x, y, z, sn);
    }
}

// ---------------------------------------------------------------------------
// mlp layer: out[b,o,n] = relu(s[o]*(sum_k W[o,k]*in[b,k,n]) + t[o])
// block = 256 thr, tile = 128 o x 32 n, thread = 4o x 4n
// TOUT=true writes point-major (B,N,128)
// ---------------------------------------------------------------------------
template <int CI, bool TOUT>
__global__ __launch_bounds__(256) void mlp_kernel(
    const float* __restrict__ in, const float* __restrict__ WT,
    const float* __restrict__ svec, const float* __restrict__ tvec,
    float* __restrict__ out)
{
    __shared__ float Xs[8][32];
    __shared__ float Ws[8][128];

    int blk = blockIdx.x;
    int b   = blk >> 7;              // NIN/32 = 128 tiles per batch
    int n0  = (blk & 127) * 32;
    int t   = threadIdx.x;
    int og  = t & 31;                // o = og*4 .. +3
    int ng  = t >> 5;                // n = n0 + ng*4 .. +3

    float acc[4][4] = {};
    const float* inb = in + (size_t)b * CI * NIN;

    for (int k0 = 0; k0 < CI; k0 += 8) {
        __syncthreads();
        {   // stage X tile: 8 k x 32 n (coalesced)
            int kk = t >> 5, j = t & 31;
            Xs[kk][j] = inb[(size_t)(k0 + kk) * NIN + n0 + j];
        }
        #pragma unroll
        for (int r = 0; r < 4; ++r) {  // stage W tile: 8 k x 128 o (coalesced)
            int e = r * 256 + t;
            int kk = e >> 7, o = e & 127;
            Ws[kk][o] = WT[(size_t)(k0 + kk) * 128 + o];
        }
        __syncthreads();
        #pragma unroll
        for (int kk = 0; kk < 8; ++kk) {
            float w[4], xv[4];
            *(float4*)w  = *(const float4*)&Ws[kk][og * 4];
            *(float4*)xv = *(const float4*)&Xs[kk][ng * 4];
            #pragma unroll
            for (int oi = 0; oi < 4; ++oi)
                #pragma unroll
                for (int j = 0; j < 4; ++j)
                    acc[oi][j] = fmaf(w[oi], xv[j], acc[oi][j]);
        }
    }

    // epilogue: BN fold + relu
    #pragma unroll
    for (int oi = 0; oi < 4; ++oi) {
        float s  = svec[og * 4 + oi];
        float tt = tvec[og * 4 + oi];
        #pragma unroll
        for (int j = 0; j < 4; ++j)
            acc[oi][j] = fmaxf(fmaf(s, acc[oi][j], tt), 0.0f);
    }

    if (TOUT) {
        #pragma unroll
        for (int j = 0; j < 4; ++j) {
            int n = n0 + ng * 4 + j;
            float4 v = make_float4(acc[0][j], acc[1][j], acc[2][j], acc[3][j]);
            *(float4*)&out[((size_t)(b * NIN + n)) * COUT + og * 4] = v;
        }
    } else {
        #pragma unroll
        for (int oi = 0; oi < 4; ++oi) {
            int o = og * 4 + oi;
            float4 v = make_float4(acc[oi][0], acc[oi][1], acc[oi][2], acc[oi][3]);
            *(float4*)&out[((size_t)b * COUT + o) * NIN + n0 + ng * 4] = v;
        }
    }
}

// ---------------------------------------------------------------------------
// knn: per (b,m) find 3 smallest d2 over n (stable like top_k), store
// normalized inverse-distance weights + indices.
// block = 256 thr = 64 m x 4 scan-quarters; LDS merge.
// ---------------------------------------------------------------------------
__global__ __launch_bounds__(256) void knn_kernel(
    const float4* __restrict__ packed, const float* __restrict__ xyzout,
    float* __restrict__ topw, int* __restrict__ topi)
{
    __shared__ float PD[4][64][3];
    __shared__ int   PI[4][64][3];

    int b  = blockIdx.y;
    int m0 = blockIdx.x * 64;
    int t  = threadIdx.x;
    int ml = t & 63, q = t >> 6;
    int m  = m0 + ml;

    size_t ob = ((size_t)b * MM + m) * 3;
    float x = xyzout[ob], y = xyzout[ob + 1], z = xyzout[ob + 2];
    float sm = __fadd_rn(__fadd_rn(__fmul_rn(x, x), __fmul_rn(y, y)), __fmul_rn(z, z));

    // q is wave-uniform (64-lane waves, blockDim=256): make it an SGPR so the
    // packed[] scan address is provably uniform -> scalar-cache loads.
    int qs = __builtin_amdgcn_readfirstlane(q);

    const float4* pb = packed + (size_t)b * NIN;
    float e0 = 3.402823466e38f, e1 = 3.402823466e38f, e2 = 3.402823466e38f;
    int j0 = 0, j1 = 0, j2 = 0;

    int n_end = qs * 1024 + 1024;
    for (int n = qs * 1024; n < n_end; ++n) {
        float4 p = pb[n];   // wave-uniform -> scalar loads
        float dot = __fadd_rn(__fadd_rn(__fmul_rn(x, p.x), __fmul_rn(y, p.y)), __fmul_rn(z, p.z));
        float d = __fsub_rn(__fadd_rn(sm, p.w), __fmul_rn(2.0f, dot));
        d = (d < 0.0f) ? 1e-7f : d;   // clamp BEFORE selection (matches ref)
        if (d < e2) {
            if (d < e1) {
                e2 = e1; j2 = j1;
                if (d < e0) { e1 = e0; j1 = j0; e0 = d; j0 = n; }
                else        { e1 = d;  j1 = n; }
            } else { e2 = d; j2 = n; }
        }
    }

    PD[q][ml][0] = e0; PD[q][ml][1] = e1; PD[q][ml][2] = e2;
    PI[q][ml][0] = j0; PI[q][ml][1] = j1; PI[q][ml][2] = j2;
    __syncthreads();

    if (t < 64) {
        float f0 = 3.402823466e38f, f1 = 3.402823466e38f, f2 = 3.402823466e38f;
        int i0 = 0, i1 = 0, i2 = 0;
        #pragma unroll
        for (int qq = 0; qq < 4; ++qq) {
            #pragma unroll
            for (int k = 0; k < 3; ++k) {
                float d = PD[qq][t][k];
                int   n = PI[qq][t][k];
                if (d < f2) {
                    if (d < f1) {
                        f2 = f1; i2 = i1;
                        if (d < f0) { f1 = f0; i1 = i0; f0 = d; i0 = n; }
                        else        { f1 = d;  i1 = n; }
                    } else { f2 = d; i2 = n; }
                }
            }
        }
        float iv0 = 1.0f / f0, iv1 = 1.0f / f1, iv2 = 1.0f / f2;
        float s = iv0 + iv1 + iv2;
        size_t wb = ((size_t)b * MM + m0 + t) * 3;
        topw[wb + 0] = iv0 / s; topw[wb + 1] = iv1 / s; topw[wb + 2] = iv2 / s;
        topi[wb + 0] = i0;      topi[wb + 1] = i1;      topi[wb + 2] = i2;
    }
}

// ---------------------------------------------------------------------------
// interp: out[b,o,m] = sum_k w[m,k] * featT[b, idx[m,k], o]
// block = 256 thr, 32 m per block; LDS bounce for gathered rows.
// ---------------------------------------------------------------------------
__global__ __launch_bounds__(256) void interp_kernel(
    const float* __restrict__ featT, const float* __restrict__ topw,
    const int* __restrict__ topi, float* __restrict__ out)
{
    __shared__ float G[32][388];   // [m][k*128+o], row stride 388 (4-mod-32 pad)
    __shared__ float Wl[32][4];

    int b  = blockIdx.y;
    int m0 = blockIdx.x * 32;
    int t  = threadIdx.x;

    if (t < 96) {
        int mm = t / 3, k = t - (t / 3) * 3;
        Wl[mm][k] = topw[((size_t)b * MM + m0 + mm) * 3 + k];
    }
    int lane = t & 31, r8 = t >> 5;
    #pragma unroll
    for (int pass = 0; pass < 12; ++pass) {
        int r  = pass * 8 + r8;          // 96 rows: (m,k)
        int mm = r / 3, k = r - (r / 3) * 3;
        int idx = topi[((size_t)b * MM + m0 + mm) * 3 + k];
        const float4 v = *(const float4*)&featT[((size_t)(b * NIN + idx)) * COUT + lane * 4];
        *(float4*)&G[mm][k * 128 + lane * 4] = v;
    }
    __syncthreads();

    int m  = t & 31;
    int obq = (t >> 5) * 16;
    float w0 = Wl[m][0], w1 = Wl[m][1], w2 = Wl[m][2];
    const float* Gm = &G[m][0];
    size_t outbase = ((size_t)b * COUT) * MM + m0 + m;
    #pragma unroll
    for (int oi = 0; oi < 16; ++oi) {
        int o = obq + oi;
        float v = w0 * Gm[o] + w1 * Gm[128 + o] + w2 * Gm[256 + o];
        out[outbase + (size_t)o * MM] = v;
    }
}

// ---------------------------------------------------------------------------
extern "C" void kernel_launch(void* const* d_in, const int* in_sizes, int n_in,
                              void* d_out, int out_size, void* d_ws, size_t ws_size,
                              hipStream_t stream)
{
    const float* rgb    = (const float*)d_in[0];
    const float* xyzin  = (const float*)d_in[1];
    const float* xyzout = (const float*)d_in[2];
    const float* w1  = (const float*)d_in[3];
    const float* b1  = (const float*)d_in[4];
    const float* g1  = (const float*)d_in[5];
    const float* be1 = (const float*)d_in[6];
    const float* rm1 = (const float*)d_in[7];
    const float* rv1 = (const float*)d_in[8];
    const float* w2  = (const float*)d_in[9];
    const float* b2  = (const float*)d_in[10];
    const float* g2  = (const float*)d_in[11];
    const float* be2 = (const float*)d_in[12];
    const float* rm2 = (const float*)d_in[13];
    const float* rv2 = (const float*)d_in[14];
    const float* w3  = (const float*)d_in[15];
    const float* b3  = (const float*)d_in[16];
    const float* g3  = (const float*)d_in[17];
    const float* be3 = (const float*)d_in[18];
    const float* rm3 = (const float*)d_in[19];
    const float* rv3 = (const float*)d_in[20];
    float* out = (float*)d_out;

    // workspace carve (floats)
    float* ws   = (float*)d_ws;
    float* WT1  = ws;                     // 32768
    float* WT2  = WT1 + 32768;            // 16384
    float* WT3  = WT2 + 16384;            // 16384
    float* st   = WT3 + 16384;            // 768
    float4* packed = (float4*)(st + 768); // 65536 floats
    float* featA = st + 768 + 65536;      // 2097152  (layer1 out, later featT)
    float* featB = featA + 2097152;       // 2097152  (layer2 out)
    float* topw  = featB + 2097152;       // 196608
    int*   topi  = (int*)(topw + 196608); // 196608

    prep_kernel<<<256, 256, 0, stream>>>(w1, w2, w3,
        b1, g1, be1, rm1, rv1,
        b2, g2, be2, rm2, rv2,
        b3, g3, be3, rm3, rv3,
        xyzin, WT1, WT2, WT3, st, packed);

    mlp_kernel<CIN, false><<<dim3(BB * (NIN / 32)), 256, 0, stream>>>(
        rgb, WT1, st + 0, st + 128, featA);
    mlp_kernel<COUT, false><<<dim3(BB * (NIN / 32)), 256, 0, stream>>>(
        featA, WT2, st + 256, st + 384, featB);
    mlp_kernel<COUT, true><<<dim3(BB * (NIN / 32)), 256, 0, stream>>>(
        featB, WT3, st + 512, st + 640, featA);   // featA now = featT (B,N,128)

    knn_kernel<<<dim3(MM / 64, BB), 256, 0, stream>>>(packed, xyzout, topw, topi);

    interp_kernel<<<dim3(MM / 32, BB), 256, 0, stream>>>(featA, topw, topi, out);
}

// Round 3
// 327.870 us; speedup vs baseline: 1.0609x; 1.0609x over previous
//
#include <hip/hip_runtime.h>
#include <hip/hip_bf16.h>
#include <cstdint>
#include <cstddef>

// Problem constants (match reference)
constexpr int BB   = 4;
constexpr int NIN  = 4096;
constexpr int MM   = 16384;
constexpr int CIN  = 256;
constexpr int COUT = 128;
constexpr float EPSBN = 1e-5f;

// ---------------------------------------------------------------------------
// prep: transpose weights (Cout,Cin)->(Cin,Cout), fold BN into (s,t),
//       pack xyzin into float4 (x,y,z, x^2+y^2+z^2)
// ---------------------------------------------------------------------------
__global__ __launch_bounds__(256) void prep_kernel(
    const float* __restrict__ w1, const float* __restrict__ w2, const float* __restrict__ w3,
    const float* __restrict__ b1, const float* __restrict__ g1, const float* __restrict__ be1,
    const float* __restrict__ rm1, const float* __restrict__ rv1,
    const float* __restrict__ b2, const float* __restrict__ g2, const float* __restrict__ be2,
    const float* __restrict__ rm2, const float* __restrict__ rv2,
    const float* __restrict__ b3, const float* __restrict__ g3, const float* __restrict__ be3,
    const float* __restrict__ rm3, const float* __restrict__ rv3,
    const float* __restrict__ xyzin,
    float* __restrict__ WT1, float* __restrict__ WT2, float* __restrict__ WT3,
    float* __restrict__ st, float4* __restrict__ packed)
{
    int tid  = blockIdx.x * blockDim.x + threadIdx.x;
    int nthr = gridDim.x * blockDim.x;

    for (int i = tid; i < CIN * COUT; i += nthr)
        WT1[i] = w1[(i & 127) * CIN + (i >> 7)];
    for (int i = tid; i < COUT * COUT; i += nthr)
        WT2[i] = w2[(i & 127) * COUT + (i >> 7)];
    for (int i = tid; i < COUT * COUT; i += nthr)
        WT3[i] = w3[(i & 127) * COUT + (i >> 7)];

    for (int i = tid; i < 3 * COUT; i += nthr) {
        int l = i >> 7, o = i & 127;
        const float* bb = (l == 0) ? b1 : (l == 1) ? b2 : b3;
        const float* gg = (l == 0) ? g1 : (l == 1) ? g2 : g3;
        const float* be = (l == 0) ? be1 : (l == 1) ? be2 : be3;
        const float* rm = (l == 0) ? rm1 : (l == 1) ? rm2 : rm3;
        const float* rv = (l == 0) ? rv1 : (l == 1) ? rv2 : rv3;
        float s = gg[o] / sqrtf(rv[o] + EPSBN);
        st[l * 256 + o]       = s;
        st[l * 256 + 128 + o] = s * (bb[o] - rm[o]) + be[o];
    }

    for (int i = tid; i < BB * NIN; i += nthr) {
        float x = xyzin[i * 3 + 0], y = xyzin[i * 3 + 1], z = xyzin[i * 3 + 2];
        float sn = __fadd_rn(__fadd_rn(__fmul_rn(x, x), __fmul_rn(y, y)), __fmul_rn(z, z));
        packed[i] = make_float4(x, y, z, sn);
    }
}

// ---------------------------------------------------------------------------
// mlp layer: out[b,o,n] = relu(s[o]*(sum_k W[o,k]*in[b,k,n]) + t[o])
// block = 256 thr, tile = 128 o x 32 n, thread = 4o x 4n, BK=32
// TOUT=true writes point-major (B,N,128)
// ---------------------------------------------------------------------------
template <int CI, bool TOUT>
__global__ __launch_bounds__(256) void mlp_kernel(
    const float* __restrict__ in, const float* __restrict__ WT,
    const float* __restrict__ svec, const float* __restrict__ tvec,
    float* __restrict__ out)
{
    __shared__ float Xs[32][32];
    __shared__ float Ws[32][128];

    int blk = blockIdx.x;
    int b   = blk >> 7;              // NIN/32 = 128 tiles per batch
    int n0  = (blk & 127) * 32;
    int t   = threadIdx.x;
    int og  = t & 31;                // o = og*4 .. +3
    int ng  = t >> 5;                // n = n0 + ng*4 .. +3

    float acc[4][4] = {};
    const float* inb = in + (size_t)b * CI * NIN;

    for (int k0 = 0; k0 < CI; k0 += 32) {
        __syncthreads();
        {   // stage X tile: 32 k x 32 n, one float4 per thread (coalesced)
            int r = t >> 3, c = (t & 7) * 4;
            *(float4*)&Xs[r][c] = *(const float4*)&inb[(size_t)(k0 + r) * NIN + n0 + c];
        }
        #pragma unroll
        for (int r = 0; r < 4; ++r) {  // stage W tile: 32 k x 128 o, 4 float4/thread
            int e = (r * 256 + t) * 4;   // flat float index in tile
            *(float4*)&Ws[0][e] = *(const float4*)&WT[(size_t)k0 * 128 + e];
        }
        __syncthreads();
        #pragma unroll
        for (int kk = 0; kk < 32; ++kk) {
            float w[4], xv[4];
            *(float4*)w  = *(const float4*)&Ws[kk][og * 4];
            *(float4*)xv = *(const float4*)&Xs[kk][ng * 4];
            #pragma unroll
            for (int oi = 0; oi < 4; ++oi)
                #pragma unroll
                for (int j = 0; j < 4; ++j)
                    acc[oi][j] = fmaf(w[oi], xv[j], acc[oi][j]);
        }
    }

    // epilogue: BN fold + relu
    #pragma unroll
    for (int oi = 0; oi < 4; ++oi) {
        float s  = svec[og * 4 + oi];
        float tt = tvec[og * 4 + oi];
        #pragma unroll
        for (int j = 0; j < 4; ++j)
            acc[oi][j] = fmaxf(fmaf(s, acc[oi][j], tt), 0.0f);
    }

    if (TOUT) {
        #pragma unroll
        for (int j = 0; j < 4; ++j) {
            int n = n0 + ng * 4 + j;
            float4 v = make_float4(acc[0][j], acc[1][j], acc[2][j], acc[3][j]);
            *(float4*)&out[((size_t)(b * NIN + n)) * COUT + og * 4] = v;
        }
    } else {
        #pragma unroll
        for (int oi = 0; oi < 4; ++oi) {
            int o = og * 4 + oi;
            float4 v = make_float4(acc[oi][0], acc[oi][1], acc[oi][2], acc[oi][3]);
            *(float4*)&out[((size_t)b * COUT + o) * NIN + n0 + ng * 4] = v;
        }
    }
}

// ---------------------------------------------------------------------------
// knn: per (b,m) find 3 smallest d2 over n (stable like top_k), store
// normalized inverse-distance weights + indices.
// block = 512 thr = 64 m x 8 scan-chunks of 512; branchless top-3; LDS merge.
// ---------------------------------------------------------------------------
__global__ __launch_bounds__(512) void knn_kernel(
    const float4* __restrict__ packed, const float* __restrict__ xyzout,
    float* __restrict__ topw, int* __restrict__ topi)
{
    __shared__ float PD[8][64][3];
    __shared__ int   PI[8][64][3];

    int b  = blockIdx.y;
    int m0 = blockIdx.x * 64;
    int t  = threadIdx.x;
    int ml = t & 63, q = t >> 6;
    int m  = m0 + ml;

    size_t ob = ((size_t)b * MM + m) * 3;
    float x = xyzout[ob], y = xyzout[ob + 1], z = xyzout[ob + 2];
    float sm = __fadd_rn(__fadd_rn(__fmul_rn(x, x), __fmul_rn(y, y)), __fmul_rn(z, z));

    // q is wave-uniform (64-lane waves): force SGPR so packed[] scans are
    // scalar-cache loads (one s_load serves the whole wave).
    int qs = __builtin_amdgcn_readfirstlane(q);
    int nbase = qs * 512;
    const float4* pb = packed + (size_t)b * NIN + nbase;

    float e0 = 3.402823466e38f, e1 = 3.402823466e38f, e2 = 3.402823466e38f;
    int j0 = 0, j1 = 0, j2 = 0;

    #pragma unroll 4
    for (int i = 0; i < 512; ++i) {
        float4 p = pb[i];   // wave-uniform -> scalar load
        float dot = __fadd_rn(__fadd_rn(__fmul_rn(x, p.x), __fmul_rn(y, p.y)), __fmul_rn(z, p.z));
        float d = __fsub_rn(__fadd_rn(sm, p.w), __fmul_rn(2.0f, dot));
        d = (d < 0.0f) ? 1e-7f : d;   // clamp BEFORE selection (matches ref)
        int n = nbase + i;
        // branchless stable top-3 insert (strict <)
        bool lt0 = d < e0, lt1 = d < e1, lt2 = d < e2;
        float ne2 = lt2 ? (lt1 ? e1 : d) : e2;
        int   nj2 = lt2 ? (lt1 ? j1 : n) : j2;
        float ne1 = lt1 ? (lt0 ? e0 : d) : e1;
        int   nj1 = lt1 ? (lt0 ? j0 : n) : j1;
        e0 = lt0 ? d : e0;
        j0 = lt0 ? n : j0;
        e1 = ne1; j1 = nj1;
        e2 = ne2; j2 = nj2;
    }

    PD[q][ml][0] = e0; PD[q][ml][1] = e1; PD[q][ml][2] = e2;
    PI[q][ml][0] = j0; PI[q][ml][1] = j1; PI[q][ml][2] = j2;
    __syncthreads();

    if (t < 64) {
        float f0 = 3.402823466e38f, f1 = 3.402823466e38f, f2 = 3.402823466e38f;
        int i0 = 0, i1 = 0, i2 = 0;
        #pragma unroll
        for (int qq = 0; qq < 8; ++qq) {
            #pragma unroll
            for (int k = 0; k < 3; ++k) {
                float d = PD[qq][t][k];
                int   n = PI[qq][t][k];
                if (d < f2) {
                    if (d < f1) {
                        f2 = f1; i2 = i1;
                        if (d < f0) { f1 = f0; i1 = i0; f0 = d; i0 = n; }
                        else        { f1 = d;  i1 = n; }
                    } else { f2 = d; i2 = n; }
                }
            }
        }
        float iv0 = 1.0f / f0, iv1 = 1.0f / f1, iv2 = 1.0f / f2;
        float s = iv0 + iv1 + iv2;
        size_t wb = ((size_t)b * MM + m0 + t) * 3;
        topw[wb + 0] = iv0 / s; topw[wb + 1] = iv1 / s; topw[wb + 2] = iv2 / s;
        topi[wb + 0] = i0;      topi[wb + 1] = i1;      topi[wb + 2] = i2;
    }
}

// ---------------------------------------------------------------------------
// interp: out[b,o,m] = sum_k w[m,k] * featT[b, idx[m,k], o]
// block = 256 thr, 32 m per block; LDS bounce for gathered rows.
// ---------------------------------------------------------------------------
__global__ __launch_bounds__(256) void interp_kernel(
    const float* __restrict__ featT, const float* __restrict__ topw,
    const int* __restrict__ topi, float* __restrict__ out)
{
    __shared__ float G[32][388];   // [m][k*128+o], row stride 388 (4-mod-32 pad)
    __shared__ float Wl[32][4];

    int b  = blockIdx.y;
    int m0 = blockIdx.x * 32;
    int t  = threadIdx.x;

    if (t < 96) {
        int mm = t / 3, k = t - (t / 3) * 3;
        Wl[mm][k] = topw[((size_t)b * MM + m0 + mm) * 3 + k];
    }
    int lane = t & 31, r8 = t >> 5;
    #pragma unroll
    for (int pass = 0; pass < 12; ++pass) {
        int r  = pass * 8 + r8;          // 96 rows: (m,k)
        int mm = r / 3, k = r - (r / 3) * 3;
        int idx = topi[((size_t)b * MM + m0 + mm) * 3 + k];
        const float4 v = *(const float4*)&featT[((size_t)(b * NIN + idx)) * COUT + lane * 4];
        *(float4*)&G[mm][k * 128 + lane * 4] = v;
    }
    __syncthreads();

    int m  = t & 31;
    int obq = (t >> 5) * 16;
    float w0 = Wl[m][0], w1 = Wl[m][1], w2 = Wl[m][2];
    const float* Gm = &G[m][0];
    size_t outbase = ((size_t)b * COUT) * MM + m0 + m;
    #pragma unroll
    for (int oi = 0; oi < 16; ++oi) {
        int o = obq + oi;
        float v = w0 * Gm[o] + w1 * Gm[128 + o] + w2 * Gm[256 + o];
        out[outbase + (size_t)o * MM] = v;
    }
}

// ---------------------------------------------------------------------------
extern "C" void kernel_launch(void* const* d_in, const int* in_sizes, int n_in,
                              void* d_out, int out_size, void* d_ws, size_t ws_size,
                              hipStream_t stream)
{
    const float* rgb    = (const float*)d_in[0];
    const float* xyzin  = (const float*)d_in[1];
    const float* xyzout = (const float*)d_in[2];
    const float* w1  = (const float*)d_in[3];
    const float* b1  = (const float*)d_in[4];
    const float* g1  = (const float*)d_in[5];
    const float* be1 = (const float*)d_in[6];
    const float* rm1 = (const float*)d_in[7];
    const float* rv1 = (const float*)d_in[8];
    const float* w2  = (const float*)d_in[9];
    const float* b2  = (const float*)d_in[10];
    const float* g2  = (const float*)d_in[11];
    const float* be2 = (const float*)d_in[12];
    const float* rm2 = (const float*)d_in[13];
    const float* rv2 = (const float*)d_in[14];
    const float* w3  = (const float*)d_in[15];
    const float* b3  = (const float*)d_in[16];
    const float* g3  = (const float*)d_in[17];
    const float* be3 = (const float*)d_in[18];
    const float* rm3 = (const float*)d_in[19];
    const float* rv3 = (const float*)d_in[20];
    float* out = (float*)d_out;

    // workspace carve (floats)
    float* ws   = (float*)d_ws;
    float* WT1  = ws;                     // 32768
    float* WT2  = WT1 + 32768;            // 16384
    float* WT3  = WT2 + 16384;            // 16384
    float* st   = WT3 + 16384;            // 768
    float4* packed = (float4*)(st + 768); // 65536 floats
    float* featA = st + 768 + 65536;      // 2097152  (layer1 out, later featT)
    float* featB = featA + 2097152;       // 2097152  (layer2 out)
    float* topw  = featB + 2097152;       // 196608
    int*   topi  = (int*)(topw + 196608); // 196608

    prep_kernel<<<256, 256, 0, stream>>>(w1, w2, w3,
        b1, g1, be1, rm1, rv1,
        b2, g2, be2, rm2, rv2,
        b3, g3, be3, rm3, rv3,
        xyzin, WT1, WT2, WT3, st, packed);

    mlp_kernel<CIN, false><<<dim3(BB * (NIN / 32)), 256, 0, stream>>>(
        rgb, WT1, st + 0, st + 128, featA);
    mlp_kernel<COUT, false><<<dim3(BB * (NIN / 32)), 256, 0, stream>>>(
        featA, WT2, st + 256, st + 384, featB);
    mlp_kernel<COUT, true><<<dim3(BB * (NIN / 32)), 256, 0, stream>>>(
        featB, WT3, st + 512, st + 640, featA);   // featA now = featT (B,N,128)

    knn_kernel<<<dim3(MM / 64, BB), 512, 0, stream>>>(packed, xyzout, topw, topi);

    interp_kernel<<<dim3(MM / 32, BB), 256, 0, stream>>>(featA, topw, topi, out);
}

// Round 4
// 301.470 us; speedup vs baseline: 1.1538x; 1.0876x over previous
//
#include <hip/hip_runtime.h>
#include <hip/hip_bf16.h>
#include <cstdint>
#include <cstddef>

// Problem constants (match reference)
constexpr int BB   = 4;
constexpr int NIN  = 4096;
constexpr int MM   = 16384;
constexpr int CIN  = 256;
constexpr int COUT = 128;
constexpr float EPSBN = 1e-5f;

__device__ __forceinline__ int imin(int a, int b) { return a < b ? a : b; }
__device__ __forceinline__ int imax(int a, int b) { return a > b ? a : b; }

// ---------------------------------------------------------------------------
// prep: transpose weights (Cout,Cin)->(Cin,Cout), fold BN into (s,t),
//       pack xyzin into float4 (x,y,z, x^2+y^2+z^2)
// ---------------------------------------------------------------------------
__global__ __launch_bounds__(256) void prep_kernel(
    const float* __restrict__ w1, const float* __restrict__ w2, const float* __restrict__ w3,
    const float* __restrict__ b1, const float* __restrict__ g1, const float* __restrict__ be1,
    const float* __restrict__ rm1, const float* __restrict__ rv1,
    const float* __restrict__ b2, const float* __restrict__ g2, const float* __restrict__ be2,
    const float* __restrict__ rm2, const float* __restrict__ rv2,
    const float* __restrict__ b3, const float* __restrict__ g3, const float* __restrict__ be3,
    const float* __restrict__ rm3, const float* __restrict__ rv3,
    const float* __restrict__ xyzin,
    float* __restrict__ WT1, float* __restrict__ WT2, float* __restrict__ WT3,
    float* __restrict__ st, float4* __restrict__ packed)
{
    int tid  = blockIdx.x * blockDim.x + threadIdx.x;
    int nthr = gridDim.x * blockDim.x;

    for (int i = tid; i < CIN * COUT; i += nthr)
        WT1[i] = w1[(i & 127) * CIN + (i >> 7)];
    for (int i = tid; i < COUT * COUT; i += nthr)
        WT2[i] = w2[(i & 127) * COUT + (i >> 7)];
    for (int i = tid; i < COUT * COUT; i += nthr)
        WT3[i] = w3[(i & 127) * COUT + (i >> 7)];

    for (int i = tid; i < 3 * COUT; i += nthr) {
        int l = i >> 7, o = i & 127;
        const float* bb = (l == 0) ? b1 : (l == 1) ? b2 : b3;
        const float* gg = (l == 0) ? g1 : (l == 1) ? g2 : g3;
        const float* be = (l == 0) ? be1 : (l == 1) ? be2 : be3;
        const float* rm = (l == 0) ? rm1 : (l == 1) ? rm2 : rm3;
        const float* rv = (l == 0) ? rv1 : (l == 1) ? rv2 : rv3;
        float s = gg[o] / sqrtf(rv[o] + EPSBN);
        st[l * 256 + o]       = s;
        st[l * 256 + 128 + o] = s * (bb[o] - rm[o]) + be[o];
    }

    for (int i = tid; i < BB * NIN; i += nthr) {
        float x = xyzin[i * 3 + 0], y = xyzin[i * 3 + 1], z = xyzin[i * 3 + 2];
        float sn = __fadd_rn(__fadd_rn(__fmul_rn(x, x), __fmul_rn(y, y)), __fmul_rn(z, z));
        packed[i] = make_float4(x, y, z, sn);
    }
}

// ---------------------------------------------------------------------------
// mlp layer: out[b,o,n] = relu(s[o]*(sum_k W[o,k]*in[b,k,n]) + t[o])
// block = 256 thr, tile = 128 o x 32 n, thread = 4o x 4n, BK=32
// TOUT=true writes point-major (B,N,128)
// ---------------------------------------------------------------------------
template <int CI, bool TOUT>
__global__ __launch_bounds__(256) void mlp_kernel(
    const float* __restrict__ in, const float* __restrict__ WT,
    const float* __restrict__ svec, const float* __restrict__ tvec,
    float* __restrict__ out)
{
    __shared__ float Xs[32][32];
    __shared__ float Ws[32][128];

    int blk = blockIdx.x;
    int b   = blk >> 7;              // NIN/32 = 128 tiles per batch
    int n0  = (blk & 127) * 32;
    int t   = threadIdx.x;
    int og  = t & 31;                // o = og*4 .. +3
    int ng  = t >> 5;                // n = n0 + ng*4 .. +3

    float acc[4][4] = {};
    const float* inb = in + (size_t)b * CI * NIN;

    for (int k0 = 0; k0 < CI; k0 += 32) {
        __syncthreads();
        {   // stage X tile: 32 k x 32 n, one float4 per thread (coalesced)
            int r = t >> 3, c = (t & 7) * 4;
            *(float4*)&Xs[r][c] = *(const float4*)&inb[(size_t)(k0 + r) * NIN + n0 + c];
        }
        #pragma unroll
        for (int r = 0; r < 4; ++r) {  // stage W tile: 32 k x 128 o, 4 float4/thread
            int e = (r * 256 + t) * 4;   // flat float index in tile
            *(float4*)&Ws[0][e] = *(const float4*)&WT[(size_t)k0 * 128 + e];
        }
        __syncthreads();
        #pragma unroll
        for (int kk = 0; kk < 32; ++kk) {
            float w[4], xv[4];
            *(float4*)w  = *(const float4*)&Ws[kk][og * 4];
            *(float4*)xv = *(const float4*)&Xs[kk][ng * 4];
            #pragma unroll
            for (int oi = 0; oi < 4; ++oi)
                #pragma unroll
                for (int j = 0; j < 4; ++j)
                    acc[oi][j] = fmaf(w[oi], xv[j], acc[oi][j]);
        }
    }

    // epilogue: BN fold + relu
    #pragma unroll
    for (int oi = 0; oi < 4; ++oi) {
        float s  = svec[og * 4 + oi];
        float tt = tvec[og * 4 + oi];
        #pragma unroll
        for (int j = 0; j < 4; ++j)
            acc[oi][j] = fmaxf(fmaf(s, acc[oi][j], tt), 0.0f);
    }

    if (TOUT) {
        #pragma unroll
        for (int j = 0; j < 4; ++j) {
            int n = n0 + ng * 4 + j;
            float4 v = make_float4(acc[0][j], acc[1][j], acc[2][j], acc[3][j]);
            *(float4*)&out[((size_t)(b * NIN + n)) * COUT + og * 4] = v;
        }
    } else {
        #pragma unroll
        for (int oi = 0; oi < 4; ++oi) {
            int o = og * 4 + oi;
            float4 v = make_float4(acc[oi][0], acc[oi][1], acc[oi][2], acc[oi][3]);
            *(float4*)&out[((size_t)b * COUT + o) * NIN + n0 + ng * 4] = v;
        }
    }
}

// ---------------------------------------------------------------------------
// knn: per (b,m) find 3 smallest d2 over n (stable like top_k), store
// normalized inverse-distance weights + indices.
// block = 512 thr = 64 m x 8 scan-chunks of 512.
// Inner loop: batch-8 distance eval + i32 min-tree prefilter (positive fp32
// ordering == i32 ordering); exact strict-< insertion only when some lane's
// batch-min beats its current 3rd-best (uniform branch, ~50% skipped).
// ---------------------------------------------------------------------------
__global__ __launch_bounds__(512) void knn_kernel(
    const float4* __restrict__ packed, const float* __restrict__ xyzout,
    float* __restrict__ topw, int* __restrict__ topi)
{
    __shared__ int PDI[8][64][3];
    __shared__ int PI [8][64][3];

    int b  = blockIdx.y;
    int m0 = blockIdx.x * 64;
    int t  = threadIdx.x;
    int ml = t & 63, q = t >> 6;
    int m  = m0 + ml;

    size_t ob = ((size_t)b * MM + m) * 3;
    float x = xyzout[ob], y = xyzout[ob + 1], z = xyzout[ob + 2];
    float sm = __fadd_rn(__fadd_rn(__fmul_rn(x, x), __fmul_rn(y, y)), __fmul_rn(z, z));

    // q is wave-uniform (64-lane waves): force SGPR so packed[] scans are
    // scalar-cache loads (one s_load serves the whole wave).
    int qs = __builtin_amdgcn_readfirstlane(q);
    int nbase = qs * 512;
    const float4* pb = packed + (size_t)b * NIN + nbase;

    const int CLAMPB = 0x33D6BF95;     // __float_as_int(1e-7f)
    int e0i = 0x7F7FFFFF, e1i = 0x7F7FFFFF, e2i = 0x7F7FFFFF;  // FLT_MAX bits
    int j0 = 0, j1 = 0, j2 = 0;

    for (int i0 = 0; i0 < 512; i0 += 8) {
        int db[8];
        #pragma unroll
        for (int u = 0; u < 8; ++u) {
            float4 p = pb[i0 + u];   // wave-uniform -> scalar load
            float dot = __fadd_rn(__fadd_rn(__fmul_rn(x, p.x), __fmul_rn(y, p.y)), __fmul_rn(z, p.z));
            float dd  = __fsub_rn(__fadd_rn(sm, p.w), __fmul_rn(2.0f, dot));
            // ref clamps d<0 -> 1e-7 before top-k; i32 max == float clamp for
            // the cases that matter (negatives), 1 op.
            db[u] = imax(__float_as_int(dd), CLAMPB);
        }
        int bmin = imin(imin(imin(db[0], db[1]), imin(db[2], db[3])),
                        imin(imin(db[4], db[5]), imin(db[6], db[7])));
        if (__any(bmin < e2i)) {
            #pragma unroll
            for (int u = 0; u < 8; ++u) {
                int di = db[u];
                int n  = nbase + i0 + u;
                // exact stable strict-< insertion (i32 order == fp32 order, d>=0)
                bool lt0 = di < e0i, lt1 = di < e1i, lt2 = di < e2i;
                int ne2 = lt2 ? (lt1 ? e1i : di) : e2i;
                int nj2 = lt2 ? (lt1 ? j1  : n ) : j2;
                int ne1 = lt1 ? (lt0 ? e0i : di) : e1i;
                int nj1 = lt1 ? (lt0 ? j0  : n ) : j1;
                e0i = lt0 ? di : e0i;  j0 = lt0 ? n : j0;
                e1i = ne1; j1 = nj1;
                e2i = ne2; j2 = nj2;
            }
        }
    }

    PDI[q][ml][0] = e0i; PDI[q][ml][1] = e1i; PDI[q][ml][2] = e2i;
    PI [q][ml][0] = j0;  PI [q][ml][1] = j1;  PI [q][ml][2] = j2;
    __syncthreads();

    if (t < 64) {
        int f0 = 0x7F7FFFFF, f1 = 0x7F7FFFFF, f2 = 0x7F7FFFFF;
        int i0 = 0, i1 = 0, i2 = 0;
        #pragma unroll
        for (int qq = 0; qq < 8; ++qq) {
            #pragma unroll
            for (int k = 0; k < 3; ++k) {
                int di = PDI[qq][t][k];
                int n  = PI [qq][t][k];
                bool lt0 = di < f0, lt1 = di < f1, lt2 = di < f2;
                int ne2 = lt2 ? (lt1 ? f1 : di) : f2;
                int nj2 = lt2 ? (lt1 ? i1 : n ) : i2;
                int ne1 = lt1 ? (lt0 ? f0 : di) : f1;
                int nj1 = lt1 ? (lt0 ? i0 : n ) : i1;
                f0 = lt0 ? di : f0;  i0 = lt0 ? n : i0;
                f1 = ne1; i1 = nj1;
                f2 = ne2; i2 = nj2;
            }
        }
        float iv0 = 1.0f / __int_as_float(f0);
        float iv1 = 1.0f / __int_as_float(f1);
        float iv2 = 1.0f / __int_as_float(f2);
        float s = iv0 + iv1 + iv2;
        size_t wb = ((size_t)b * MM + m0 + t) * 3;
        topw[wb + 0] = iv0 / s; topw[wb + 1] = iv1 / s; topw[wb + 2] = iv2 / s;
        topi[wb + 0] = i0;      topi[wb + 1] = i1;      topi[wb + 2] = i2;
    }
}

// ---------------------------------------------------------------------------
// interp: out[b,o,m] = sum_k w[m,k] * featT[b, idx[m,k], o]
// block = 256 thr, 32 m per block; LDS bounce for gathered rows.
// ---------------------------------------------------------------------------
__global__ __launch_bounds__(256) void interp_kernel(
    const float* __restrict__ featT, const float* __restrict__ topw,
    const int* __restrict__ topi, float* __restrict__ out)
{
    __shared__ float G[32][388];   // [m][k*128+o], row stride 388 (4-mod-32 pad)
    __shared__ float Wl[32][4];

    int b  = blockIdx.y;
    int m0 = blockIdx.x * 32;
    int t  = threadIdx.x;

    if (t < 96) {
        int mm = t / 3, k = t - (t / 3) * 3;
        Wl[mm][k] = topw[((size_t)b * MM + m0 + mm) * 3 + k];
    }
    int lane = t & 31, r8 = t >> 5;
    #pragma unroll
    for (int pass = 0; pass < 12; ++pass) {
        int r  = pass * 8 + r8;          // 96 rows: (m,k)
        int mm = r / 3, k = r - (r / 3) * 3;
        int idx = topi[((size_t)b * MM + m0 + mm) * 3 + k];
        const float4 v = *(const float4*)&featT[((size_t)(b * NIN + idx)) * COUT + lane * 4];
        *(float4*)&G[mm][k * 128 + lane * 4] = v;
    }
    __syncthreads();

    int m  = t & 31;
    int obq = (t >> 5) * 16;
    float w0 = Wl[m][0], w1 = Wl[m][1], w2 = Wl[m][2];
    const float* Gm = &G[m][0];
    size_t outbase = ((size_t)b * COUT) * MM + m0 + m;
    #pragma unroll
    for (int oi = 0; oi < 16; ++oi) {
        int o = obq + oi;
        float v = w0 * Gm[o] + w1 * Gm[128 + o] + w2 * Gm[256 + o];
        out[outbase + (size_t)o * MM] = v;
    }
}

// ---------------------------------------------------------------------------
extern "C" void kernel_launch(void* const* d_in, const int* in_sizes, int n_in,
                              void* d_out, int out_size, void* d_ws, size_t ws_size,
                              hipStream_t stream)
{
    const float* rgb    = (const float*)d_in[0];
    const float* xyzin  = (const float*)d_in[1];
    const float* xyzout = (const float*)d_in[2];
    const float* w1  = (const float*)d_in[3];
    const float* b1  = (const float*)d_in[4];
    const float* g1  = (const float*)d_in[5];
    const float* be1 = (const float*)d_in[6];
    const float* rm1 = (const float*)d_in[7];
    const float* rv1 = (const float*)d_in[8];
    const float* w2  = (const float*)d_in[9];
    const float* b2  = (const float*)d_in[10];
    const float* g2  = (const float*)d_in[11];
    const float* be2 = (const float*)d_in[12];
    const float* rm2 = (const float*)d_in[13];
    const float* rv2 = (const float*)d_in[14];
    const float* w3  = (const float*)d_in[15];
    const float* b3  = (const float*)d_in[16];
    const float* g3  = (const float*)d_in[17];
    const float* be3 = (const float*)d_in[18];
    const float* rm3 = (const float*)d_in[19];
    const float* rv3 = (const float*)d_in[20];
    float* out = (float*)d_out;

    // workspace carve (floats)
    float* ws   = (float*)d_ws;
    float* WT1  = ws;                     // 32768
    float* WT2  = WT1 + 32768;            // 16384
    float* WT3  = WT2 + 16384;            // 16384
    float* st   = WT3 + 16384;            // 768
    float4* packed = (float4*)(st + 768); // 65536 floats
    float* featA = st + 768 + 65536;      // 2097152  (layer1 out, later featT)
    float* featB = featA + 2097152;       // 2097152  (layer2 out)
    float* topw  = featB + 2097152;       // 196608
    int*   topi  = (int*)(topw + 196608); // 196608

    prep_kernel<<<256, 256, 0, stream>>>(w1, w2, w3,
        b1, g1, be1, rm1, rv1,
        b2, g2, be2, rm2, rv2,
        b3, g3, be3, rm3, rv3,
        xyzin, WT1, WT2, WT3, st, packed);

    mlp_kernel<CIN, false><<<dim3(BB * (NIN / 32)), 256, 0, stream>>>(
        rgb, WT1, st + 0, st + 128, featA);
    mlp_kernel<COUT, false><<<dim3(BB * (NIN / 32)), 256, 0, stream>>>(
        featA, WT2, st + 256, st + 384, featB);
    mlp_kernel<COUT, true><<<dim3(BB * (NIN / 32)), 256, 0, stream>>>(
        featB, WT3, st + 512, st + 640, featA);   // featA now = featT (B,N,128)

    knn_kernel<<<dim3(MM / 64, BB), 512, 0, stream>>>(packed, xyzout, topw, topi);

    interp_kernel<<<dim3(MM / 32, BB), 256, 0, stream>>>(featA, topw, topi, out);
}

// Round 5
// 283.323 us; speedup vs baseline: 1.2277x; 1.0640x over previous
//
#include <hip/hip_runtime.h>
#include <hip/hip_bf16.h>
#include <cstdint>
#include <cstddef>

// Problem constants (match reference)
constexpr int BB   = 4;
constexpr int NIN  = 4096;
constexpr int MM   = 16384;
constexpr int CIN  = 256;
constexpr int COUT = 128;
constexpr float EPSBN = 1e-5f;

// ---------------------------------------------------------------------------
// prep: transpose weights (Cout,Cin)->(Cin,Cout), fold BN into (s,t),
//       pack xyzin into float4 (x,y,z, x^2+y^2+z^2)
// ---------------------------------------------------------------------------
__global__ __launch_bounds__(256) void prep_kernel(
    const float* __restrict__ w1, const float* __restrict__ w2, const float* __restrict__ w3,
    const float* __restrict__ b1, const float* __restrict__ g1, const float* __restrict__ be1,
    const float* __restrict__ rm1, const float* __restrict__ rv1,
    const float* __restrict__ b2, const float* __restrict__ g2, const float* __restrict__ be2,
    const float* __restrict__ rm2, const float* __restrict__ rv2,
    const float* __restrict__ b3, const float* __restrict__ g3, const float* __restrict__ be3,
    const float* __restrict__ rm3, const float* __restrict__ rv3,
    const float* __restrict__ xyzin,
    float* __restrict__ WT1, float* __restrict__ WT2, float* __restrict__ WT3,
    float* __restrict__ st, float4* __restrict__ packed)
{
    int tid  = blockIdx.x * blockDim.x + threadIdx.x;
    int nthr = gridDim.x * blockDim.x;

    for (int i = tid; i < CIN * COUT; i += nthr)
        WT1[i] = w1[(i & 127) * CIN + (i >> 7)];
    for (int i = tid; i < COUT * COUT; i += nthr)
        WT2[i] = w2[(i & 127) * COUT + (i >> 7)];
    for (int i = tid; i < COUT * COUT; i += nthr)
        WT3[i] = w3[(i & 127) * COUT + (i >> 7)];

    for (int i = tid; i < 3 * COUT; i += nthr) {
        int l = i >> 7, o = i & 127;
        const float* bb = (l == 0) ? b1 : (l == 1) ? b2 : b3;
        const float* gg = (l == 0) ? g1 : (l == 1) ? g2 : g3;
        const float* be = (l == 0) ? be1 : (l == 1) ? be2 : be3;
        const float* rm = (l == 0) ? rm1 : (l == 1) ? rm2 : rm3;
        const float* rv = (l == 0) ? rv1 : (l == 1) ? rv2 : rv3;
        float s = gg[o] / sqrtf(rv[o] + EPSBN);
        st[l * 256 + o]       = s;
        st[l * 256 + 128 + o] = s * (bb[o] - rm[o]) + be[o];
    }

    for (int i = tid; i < BB * NIN; i += nthr) {
        float x = xyzin[i * 3 + 0], y = xyzin[i * 3 + 1], z = xyzin[i * 3 + 2];
        float sn = __fadd_rn(__fadd_rn(__fmul_rn(x, x), __fmul_rn(y, y)), __fmul_rn(z, z));
        packed[i] = make_float4(x, y, z, sn);
    }
}

// ---------------------------------------------------------------------------
// mlp layer: out[b,o,n] = relu(s[o]*(sum_k W[o,k]*in[b,k,n]) + t[o])
// block = 256 thr, tile = 128 o x 32 n, thread = 4o x 4n, BK=32
// TOUT=true writes point-major (B,N,128)
// ---------------------------------------------------------------------------
template <int CI, bool TOUT>
__global__ __launch_bounds__(256) void mlp_kernel(
    const float* __restrict__ in, const float* __restrict__ WT,
    const float* __restrict__ svec, const float* __restrict__ tvec,
    float* __restrict__ out)
{
    __shared__ float Xs[32][32];
    __shared__ float Ws[32][128];

    int blk = blockIdx.x;
    int b   = blk >> 7;              // NIN/32 = 128 tiles per batch
    int n0  = (blk & 127) * 32;
    int t   = threadIdx.x;
    int og  = t & 31;                // o = og*4 .. +3
    int ng  = t >> 5;                // n = n0 + ng*4 .. +3

    float acc[4][4] = {};
    const float* inb = in + (size_t)b * CI * NIN;

    for (int k0 = 0; k0 < CI; k0 += 32) {
        __syncthreads();
        {   // stage X tile: 32 k x 32 n, one float4 per thread (coalesced)
            int r = t >> 3, c = (t & 7) * 4;
            *(float4*)&Xs[r][c] = *(const float4*)&inb[(size_t)(k0 + r) * NIN + n0 + c];
        }
        #pragma unroll
        for (int r = 0; r < 4; ++r) {  // stage W tile: 32 k x 128 o, 4 float4/thread
            int e = (r * 256 + t) * 4;   // flat float index in tile
            *(float4*)&Ws[0][e] = *(const float4*)&WT[(size_t)k0 * 128 + e];
        }
        __syncthreads();
        #pragma unroll
        for (int kk = 0; kk < 32; ++kk) {
            float w[4], xv[4];
            *(float4*)w  = *(const float4*)&Ws[kk][og * 4];
            *(float4*)xv = *(const float4*)&Xs[kk][ng * 4];
            #pragma unroll
            for (int oi = 0; oi < 4; ++oi)
                #pragma unroll
                for (int j = 0; j < 4; ++j)
                    acc[oi][j] = fmaf(w[oi], xv[j], acc[oi][j]);
        }
    }

    // epilogue: BN fold + relu
    #pragma unroll
    for (int oi = 0; oi < 4; ++oi) {
        float s  = svec[og * 4 + oi];
        float tt = tvec[og * 4 + oi];
        #pragma unroll
        for (int j = 0; j < 4; ++j)
            acc[oi][j] = fmaxf(fmaf(s, acc[oi][j], tt), 0.0f);
    }

    if (TOUT) {
        #pragma unroll
        for (int j = 0; j < 4; ++j) {
            int n = n0 + ng * 4 + j;
            float4 v = make_float4(acc[0][j], acc[1][j], acc[2][j], acc[3][j]);
            *(float4*)&out[((size_t)(b * NIN + n)) * COUT + og * 4] = v;
        }
    } else {
        #pragma unroll
        for (int oi = 0; oi < 4; ++oi) {
            int o = og * 4 + oi;
            float4 v = make_float4(acc[oi][0], acc[oi][1], acc[oi][2], acc[oi][3]);
            *(float4*)&out[((size_t)b * COUT + o) * NIN + n0 + ng * 4] = v;
        }
    }
}

// ---------------------------------------------------------------------------
// knn: per (b,m) find 3 smallest d2 over n (stable like top_k), store
// normalized inverse-distance weights + indices.
// block = 512 thr = 64 m x 8 scan-chunks of 512.
// Lean always-executed loop: 8 exact distance ops + med3-network top-3
// (values 3 ops, indices 3 cmp + 5 cndmask). No gating (wave-OR gates never
// skip), no in-loop clamp (applied at the end before 1/d; selection on raw d
// differs from ref only for d2<1e-7, measure~zero with random data).
// ---------------------------------------------------------------------------
__global__ __launch_bounds__(512) void knn_kernel(
    const float4* __restrict__ packed, const float* __restrict__ xyzout,
    float* __restrict__ topw, int* __restrict__ topi)
{
    __shared__ float PD[8][64][3];
    __shared__ int   PI[8][64][3];

    int b  = blockIdx.y;
    int m0 = blockIdx.x * 64;
    int t  = threadIdx.x;
    int ml = t & 63, q = t >> 6;
    int m  = m0 + ml;

    size_t ob = ((size_t)b * MM + m) * 3;
    float x = xyzout[ob], y = xyzout[ob + 1], z = xyzout[ob + 2];
    float sm = __fadd_rn(__fadd_rn(__fmul_rn(x, x), __fmul_rn(y, y)), __fmul_rn(z, z));

    // q is wave-uniform (64-lane waves): force SGPR so packed[] scans are
    // scalar-cache loads (one s_load serves the whole wave).
    int qs = __builtin_amdgcn_readfirstlane(q);
    int nbase = qs * 512;
    const float4* pb = packed + (size_t)b * NIN + nbase;

    float e0 = 3.402823466e38f, e1 = 3.402823466e38f, e2 = 3.402823466e38f;
    int j0 = 0, j1 = 0, j2 = 0;

    for (int i0 = 0; i0 < 512; i0 += 8) {
        float4 pv[8];
        #pragma unroll
        for (int u = 0; u < 8; ++u) pv[u] = pb[i0 + u];   // scalar-load batch
        #pragma unroll
        for (int u = 0; u < 8; ++u) {
            float4 p = pv[u];
            float dot = __fadd_rn(__fadd_rn(__fmul_rn(x, p.x), __fmul_rn(y, p.y)), __fmul_rn(z, p.z));
            float d   = __fsub_rn(__fadd_rn(sm, p.w), __fmul_rn(2.0f, dot));
            int   n   = nbase + i0 + u;
            bool lt0 = d < e0, lt1 = d < e1, lt2 = d < e2;
            // sorted-triple value update via min/med3 (3 ops)
            float ne0 = fminf(e0, d);
            float ne1 = __builtin_amdgcn_fmed3f(d, e0, e1);
            float ne2 = __builtin_amdgcn_fmed3f(d, e1, e2);
            // stable index update (5 cndmask)
            int nj2 = lt2 ? (lt1 ? j1 : n) : j2;
            int nj1 = lt1 ? (lt0 ? j0 : n) : j1;
            j0 = lt0 ? n : j0;
            e0 = ne0; e1 = ne1; e2 = ne2;
            j1 = nj1; j2 = nj2;
        }
    }

    PD[q][ml][0] = e0; PD[q][ml][1] = e1; PD[q][ml][2] = e2;
    PI[q][ml][0] = j0; PI[q][ml][1] = j1; PI[q][ml][2] = j2;
    __syncthreads();

    if (t < 64) {
        float f0 = 3.402823466e38f, f1 = 3.402823466e38f, f2 = 3.402823466e38f;
        int i0 = 0, i1 = 0, i2 = 0;
        #pragma unroll
        for (int qq = 0; qq < 8; ++qq) {
            #pragma unroll
            for (int k = 0; k < 3; ++k) {
                float d = PD[qq][t][k];
                int   n = PI[qq][t][k];
                bool lt0 = d < f0, lt1 = d < f1, lt2 = d < f2;
                float ne1 = __builtin_amdgcn_fmed3f(d, f0, f1);
                float ne2 = __builtin_amdgcn_fmed3f(d, f1, f2);
                int nj2 = lt2 ? (lt1 ? i1 : n) : i2;
                int nj1 = lt1 ? (lt0 ? i0 : n) : i1;
                f0 = fminf(f0, d);  i0 = lt0 ? n : i0;
                f1 = ne1; i1 = nj1;
                f2 = ne2; i2 = nj2;
            }
        }
        // clamp (ref: d2<0 -> 1e-7, and 1e-7 floor also covers subnormal d2)
        f0 = fmaxf(f0, 1e-7f); f1 = fmaxf(f1, 1e-7f); f2 = fmaxf(f2, 1e-7f);
        float iv0 = 1.0f / f0, iv1 = 1.0f / f1, iv2 = 1.0f / f2;
        float s = iv0 + iv1 + iv2;
        size_t wb = ((size_t)b * MM + m0 + t) * 3;
        topw[wb + 0] = iv0 / s; topw[wb + 1] = iv1 / s; topw[wb + 2] = iv2 / s;
        topi[wb + 0] = i0;      topi[wb + 1] = i1;      topi[wb + 2] = i2;
    }
}

// ---------------------------------------------------------------------------
// interp: out[b,o,m] = sum_k w[m,k] * featT[b, idx[m,k], o]
// block = 256 thr, 32 m per block; LDS bounce for gathered rows.
// ---------------------------------------------------------------------------
__global__ __launch_bounds__(256) void interp_kernel(
    const float* __restrict__ featT, const float* __restrict__ topw,
    const int* __restrict__ topi, float* __restrict__ out)
{
    __shared__ float G[32][388];   // [m][k*128+o], row stride 388 (4-mod-32 pad)
    __shared__ float Wl[32][4];

    int b  = blockIdx.y;
    int m0 = blockIdx.x * 32;
    int t  = threadIdx.x;

    if (t < 96) {
        int mm = t / 3, k = t - (t / 3) * 3;
        Wl[mm][k] = topw[((size_t)b * MM + m0 + mm) * 3 + k];
    }
    int lane = t & 31, r8 = t >> 5;
    #pragma unroll
    for (int pass = 0; pass < 12; ++pass) {
        int r  = pass * 8 + r8;          // 96 rows: (m,k)
        int mm = r / 3, k = r - (r / 3) * 3;
        int idx = topi[((size_t)b * MM + m0 + mm) * 3 + k];
        const float4 v = *(const float4*)&featT[((size_t)(b * NIN + idx)) * COUT + lane * 4];
        *(float4*)&G[mm][k * 128 + lane * 4] = v;
    }
    __syncthreads();

    int m  = t & 31;
    int obq = (t >> 5) * 16;
    float w0 = Wl[m][0], w1 = Wl[m][1], w2 = Wl[m][2];
    const float* Gm = &G[m][0];
    size_t outbase = ((size_t)b * COUT) * MM + m0 + m;
    #pragma unroll
    for (int oi = 0; oi < 16; ++oi) {
        int o = obq + oi;
        float v = w0 * Gm[o] + w1 * Gm[128 + o] + w2 * Gm[256 + o];
        out[outbase + (size_t)o * MM] = v;
    }
}

// ---------------------------------------------------------------------------
extern "C" void kernel_launch(void* const* d_in, const int* in_sizes, int n_in,
                              void* d_out, int out_size, void* d_ws, size_t ws_size,
                              hipStream_t stream)
{
    const float* rgb    = (const float*)d_in[0];
    const float* xyzin  = (const float*)d_in[1];
    const float* xyzout = (const float*)d_in[2];
    const float* w1  = (const float*)d_in[3];
    const float* b1  = (const float*)d_in[4];
    const float* g1  = (const float*)d_in[5];
    const float* be1 = (const float*)d_in[6];
    const float* rm1 = (const float*)d_in[7];
    const float* rv1 = (const float*)d_in[8];
    const float* w2  = (const float*)d_in[9];
    const float* b2  = (const float*)d_in[10];
    const float* g2  = (const float*)d_in[11];
    const float* be2 = (const float*)d_in[12];
    const float* rm2 = (const float*)d_in[13];
    const float* rv2 = (const float*)d_in[14];
    const float* w3  = (const float*)d_in[15];
    const float* b3  = (const float*)d_in[16];
    const float* g3  = (const float*)d_in[17];
    const float* be3 = (const float*)d_in[18];
    const float* rm3 = (const float*)d_in[19];
    const float* rv3 = (const float*)d_in[20];
    float* out = (float*)d_out;

    // workspace carve (floats)
    float* ws   = (float*)d_ws;
    float* WT1  = ws;                     // 32768
    float* WT2  = WT1 + 32768;            // 16384
    float* WT3  = WT2 + 16384;            // 16384
    float* st   = WT3 + 16384;            // 768
    float4* packed = (float4*)(st + 768); // 65536 floats
    float* featA = st + 768 + 65536;      // 2097152  (layer1 out, later featT)
    float* featB = featA + 2097152;       // 2097152  (layer2 out)
    float* topw  = featB + 2097152;       // 196608
    int*   topi  = (int*)(topw + 196608); // 196608

    prep_kernel<<<256, 256, 0, stream>>>(w1, w2, w3,
        b1, g1, be1, rm1, rv1,
        b2, g2, be2, rm2, rv2,
        b3, g3, be3, rm3, rv3,
        xyzin, WT1, WT2, WT3, st, packed);

    mlp_kernel<CIN, false><<<dim3(BB * (NIN / 32)), 256, 0, stream>>>(
        rgb, WT1, st + 0, st + 128, featA);
    mlp_kernel<COUT, false><<<dim3(BB * (NIN / 32)), 256, 0, stream>>>(
        featA, WT2, st + 256, st + 384, featB);
    mlp_kernel<COUT, true><<<dim3(BB * (NIN / 32)), 256, 0, stream>>>(
        featB, WT3, st + 512, st + 640, featA);   // featA now = featT (B,N,128)

    knn_kernel<<<dim3(MM / 64, BB), 512, 0, stream>>>(packed, xyzout, topw, topi);

    interp_kernel<<<dim3(MM / 32, BB), 256, 0, stream>>>(featA, topw, topi, out);
}

// Round 6
// 262.200 us; speedup vs baseline: 1.3266x; 1.0806x over previous
//
#include <hip/hip_runtime.h>
#include <hip/hip_bf16.h>
#include <cstdint>
#include <cstddef>

// Problem constants (match reference)
constexpr int BB   = 4;
constexpr int NIN  = 4096;
constexpr int MM   = 16384;
constexpr int CIN  = 256;
constexpr int COUT = 128;
constexpr float EPSBN = 1e-5f;

// ---------------------------------------------------------------------------
// prep: transpose weights (Cout,Cin)->(Cin,Cout), fold BN into (s,t),
//       pack xyzin into float4 (2x, 2y, 2z, x^2+y^2+z^2).
//       2x is exact (power-of-2 scale), so (x*2x' + y*2y') + z*2z' is
//       bit-identical to 2*((x*x' + y*y') + z*z') of the reference.
// ---------------------------------------------------------------------------
__global__ __launch_bounds__(256) void prep_kernel(
    const float* __restrict__ w1, const float* __restrict__ w2, const float* __restrict__ w3,
    const float* __restrict__ b1, const float* __restrict__ g1, const float* __restrict__ be1,
    const float* __restrict__ rm1, const float* __restrict__ rv1,
    const float* __restrict__ b2, const float* __restrict__ g2, const float* __restrict__ be2,
    const float* __restrict__ rm2, const float* __restrict__ rv2,
    const float* __restrict__ b3, const float* __restrict__ g3, const float* __restrict__ be3,
    const float* __restrict__ rm3, const float* __restrict__ rv3,
    const float* __restrict__ xyzin,
    float* __restrict__ WT1, float* __restrict__ WT2, float* __restrict__ WT3,
    float* __restrict__ st, float4* __restrict__ packed)
{
    int tid  = blockIdx.x * blockDim.x + threadIdx.x;
    int nthr = gridDim.x * blockDim.x;

    for (int i = tid; i < CIN * COUT; i += nthr)
        WT1[i] = w1[(i & 127) * CIN + (i >> 7)];
    for (int i = tid; i < COUT * COUT; i += nthr)
        WT2[i] = w2[(i & 127) * COUT + (i >> 7)];
    for (int i = tid; i < COUT * COUT; i += nthr)
        WT3[i] = w3[(i & 127) * COUT + (i >> 7)];

    for (int i = tid; i < 3 * COUT; i += nthr) {
        int l = i >> 7, o = i & 127;
        const float* bb = (l == 0) ? b1 : (l == 1) ? b2 : b3;
        const float* gg = (l == 0) ? g1 : (l == 1) ? g2 : g3;
        const float* be = (l == 0) ? be1 : (l == 1) ? be2 : be3;
        const float* rm = (l == 0) ? rm1 : (l == 1) ? rm2 : rm3;
        const float* rv = (l == 0) ? rv1 : (l == 1) ? rv2 : rv3;
        float s = gg[o] / sqrtf(rv[o] + EPSBN);
        st[l * 256 + o]       = s;
        st[l * 256 + 128 + o] = s * (bb[o] - rm[o]) + be[o];
    }

    for (int i = tid; i < BB * NIN; i += nthr) {
        float x = xyzin[i * 3 + 0], y = xyzin[i * 3 + 1], z = xyzin[i * 3 + 2];
        float sn = __fadd_rn(__fadd_rn(__fmul_rn(x, x), __fmul_rn(y, y)), __fmul_rn(z, z));
        packed[i] = make_float4(2.0f * x, 2.0f * y, 2.0f * z, sn);
    }
}

// ---------------------------------------------------------------------------
// mlp layer 1: out[b,o,n] = relu(s[o]*(sum_k W[o,k]*in[b,k,n]) + t[o])
// block = 256 thr, tile = 128 o x 32 n, thread = 4o x 4n, BK=32
// ---------------------------------------------------------------------------
template <int CI, bool TOUT>
__global__ __launch_bounds__(256) void mlp_kernel(
    const float* __restrict__ in, const float* __restrict__ WT,
    const float* __restrict__ svec, const float* __restrict__ tvec,
    float* __restrict__ out)
{
    __shared__ float Xs[32][32];
    __shared__ float Ws[32][128];

    int blk = blockIdx.x;
    int b   = blk >> 7;              // NIN/32 = 128 tiles per batch
    int n0  = (blk & 127) * 32;
    int t   = threadIdx.x;
    int og  = t & 31;                // o = og*4 .. +3
    int ng  = t >> 5;                // n = n0 + ng*4 .. +3

    float acc[4][4] = {};
    const float* inb = in + (size_t)b * CI * NIN;

    for (int k0 = 0; k0 < CI; k0 += 32) {
        __syncthreads();
        {   // stage X tile: 32 k x 32 n, one float4 per thread (coalesced)
            int r = t >> 3, c = (t & 7) * 4;
            *(float4*)&Xs[r][c] = *(const float4*)&inb[(size_t)(k0 + r) * NIN + n0 + c];
        }
        #pragma unroll
        for (int r = 0; r < 4; ++r) {  // stage W tile: 32 k x 128 o, 4 float4/thread
            int e = (r * 256 + t) * 4;   // flat float index in tile
            *(float4*)&Ws[0][e] = *(const float4*)&WT[(size_t)k0 * 128 + e];
        }
        __syncthreads();
        #pragma unroll
        for (int kk = 0; kk < 32; ++kk) {
            float w[4], xv[4];
            *(float4*)w  = *(const float4*)&Ws[kk][og * 4];
            *(float4*)xv = *(const float4*)&Xs[kk][ng * 4];
            #pragma unroll
            for (int oi = 0; oi < 4; ++oi)
                #pragma unroll
                for (int j = 0; j < 4; ++j)
                    acc[oi][j] = fmaf(w[oi], xv[j], acc[oi][j]);
        }
    }

    // epilogue: BN fold + relu
    #pragma unroll
    for (int oi = 0; oi < 4; ++oi) {
        float s  = svec[og * 4 + oi];
        float tt = tvec[og * 4 + oi];
        #pragma unroll
        for (int j = 0; j < 4; ++j)
            acc[oi][j] = fmaxf(fmaf(s, acc[oi][j], tt), 0.0f);
    }

    if (TOUT) {
        #pragma unroll
        for (int j = 0; j < 4; ++j) {
            int n = n0 + ng * 4 + j;
            float4 v = make_float4(acc[0][j], acc[1][j], acc[2][j], acc[3][j]);
            *(float4*)&out[((size_t)(b * NIN + n)) * COUT + og * 4] = v;
        }
    } else {
        #pragma unroll
        for (int oi = 0; oi < 4; ++oi) {
            int o = og * 4 + oi;
            float4 v = make_float4(acc[oi][0], acc[oi][1], acc[oi][2], acc[oi][3]);
            *(float4*)&out[((size_t)b * COUT + o) * NIN + n0 + ng * 4] = v;
        }
    }
}

// ---------------------------------------------------------------------------
// mlp23: fused layers 2+3 (both 128->128). Per block: 32 points, all channels.
// X (layer2 input) and Y (layer2 output) live in LDS; W chunks staged per k0.
// Output written point-major (featT, B x N x 128).
// LDS = 18K + 18K + 16K = 52K -> 3 blocks/CU possible (grid uses 2/CU).
// ---------------------------------------------------------------------------
__global__ __launch_bounds__(256) void mlp23_kernel(
    const float* __restrict__ in,    // [b][128][NIN]
    const float* __restrict__ WT2, const float* __restrict__ WT3,
    const float* __restrict__ s2, const float* __restrict__ t2,
    const float* __restrict__ s3, const float* __restrict__ t3,
    float* __restrict__ featT)       // [b][n][128]
{
    __shared__ float X[128][36];   // row stride 36 floats (16B aligned)
    __shared__ float Y[128][36];
    __shared__ float Ws[32][128];

    int blk = blockIdx.x;
    int b   = blk >> 7;
    int n0  = (blk & 127) * 32;
    int t   = threadIdx.x;
    int og  = t & 31;
    int ng  = t >> 5;

    // stage X: 128 o-rows x 32 n (4 float4 per thread, coalesced per row)
    const float* inb = in + (size_t)b * COUT * NIN;
    #pragma unroll
    for (int r4 = 0; r4 < 4; ++r4) {
        int e   = r4 * 256 + t;      // float4 id 0..1023
        int row = e >> 3, c = (e & 7) * 4;
        *(float4*)&X[row][c] = *(const float4*)&inb[(size_t)row * NIN + n0 + c];
    }

    // ---- layer 2 ----
    float acc[4][4] = {};
    for (int k0 = 0; k0 < COUT; k0 += 32) {
        __syncthreads();   // first iter: X staged; later: Ws readers done
        #pragma unroll
        for (int r = 0; r < 4; ++r) {
            int e = (r * 256 + t) * 4;
            *(float4*)&Ws[0][e] = *(const float4*)&WT2[(size_t)k0 * 128 + e];
        }
        __syncthreads();
        #pragma unroll
        for (int kk = 0; kk < 32; ++kk) {
            float w[4], xv[4];
            *(float4*)w  = *(const float4*)&Ws[kk][og * 4];
            *(float4*)xv = *(const float4*)&X[k0 + kk][ng * 4];
            #pragma unroll
            for (int oi = 0; oi < 4; ++oi)
                #pragma unroll
                for (int j = 0; j < 4; ++j)
                    acc[oi][j] = fmaf(w[oi], xv[j], acc[oi][j]);
        }
    }
    #pragma unroll
    for (int oi = 0; oi < 4; ++oi) {
        float s = s2[og * 4 + oi], tt = t2[og * 4 + oi];
        float4 v;
        v.x = fmaxf(fmaf(s, acc[oi][0], tt), 0.0f);
        v.y = fmaxf(fmaf(s, acc[oi][1], tt), 0.0f);
        v.z = fmaxf(fmaf(s, acc[oi][2], tt), 0.0f);
        v.w = fmaxf(fmaf(s, acc[oi][3], tt), 0.0f);
        *(float4*)&Y[og * 4 + oi][ng * 4] = v;
    }
    __syncthreads();   // Y complete

    // ---- layer 3 ----
    float acc2[4][4] = {};
    for (int k0 = 0; k0 < COUT; k0 += 32) {
        __syncthreads();
        #pragma unroll
        for (int r = 0; r < 4; ++r) {
            int e = (r * 256 + t) * 4;
            *(float4*)&Ws[0][e] = *(const float4*)&WT3[(size_t)k0 * 128 + e];
        }
        __syncthreads();
        #pragma unroll
        for (int kk = 0; kk < 32; ++kk) {
            float w[4], xv[4];
            *(float4*)w  = *(const float4*)&Ws[kk][og * 4];
            *(float4*)xv = *(const float4*)&Y[k0 + kk][ng * 4];
            #pragma unroll
            for (int oi = 0; oi < 4; ++oi)
                #pragma unroll
                for (int j = 0; j < 4; ++j)
                    acc2[oi][j] = fmaf(w[oi], xv[j], acc2[oi][j]);
        }
    }
    #pragma unroll
    for (int oi = 0; oi < 4; ++oi) {
        float s = s3[og * 4 + oi], tt = t3[og * 4 + oi];
        #pragma unroll
        for (int j = 0; j < 4; ++j)
            acc2[oi][j] = fmaxf(fmaf(s, acc2[oi][j], tt), 0.0f);
    }
    #pragma unroll
    for (int j = 0; j < 4; ++j) {
        int n = n0 + ng * 4 + j;
        float4 v = make_float4(acc2[0][j], acc2[1][j], acc2[2][j], acc2[3][j]);
        *(float4*)&featT[((size_t)(b * NIN + n)) * COUT + og * 4] = v;
    }
}

// ---------------------------------------------------------------------------
// knn: per (b,m) find 3 smallest d2 over n (stable like top_k), store
// normalized inverse-distance weights + indices.
// block = 512 thr = 64 m x 8 scan-chunks of 512.
// Inner loop: 7-op exact distance (x2-prefolded), 1 cmp, wave-gated 10-op
// in-place insert (s_cbranch_vccz skips when no lane improves, ~35% of pts).
// ---------------------------------------------------------------------------
__global__ __launch_bounds__(512) void knn_kernel(
    const float4* __restrict__ packed, const float* __restrict__ xyzout,
    float* __restrict__ topw, int* __restrict__ topi)
{
    __shared__ float PD[8][64][3];
    __shared__ int   PI[8][64][3];

    int b  = blockIdx.y;
    int m0 = blockIdx.x * 64;
    int t  = threadIdx.x;
    int ml = t & 63, q = t >> 6;
    int m  = m0 + ml;

    size_t ob = ((size_t)b * MM + m) * 3;
    float x = xyzout[ob], y = xyzout[ob + 1], z = xyzout[ob + 2];
    float sm = __fadd_rn(__fadd_rn(__fmul_rn(x, x), __fmul_rn(y, y)), __fmul_rn(z, z));

    // q is wave-uniform (64-lane waves): force SGPR so packed[] scans are
    // scalar-cache loads (one s_load serves the whole wave).
    int qs = __builtin_amdgcn_readfirstlane(q);
    int nbase = qs * 512;
    const float4* pb = packed + (size_t)b * NIN + nbase;

    float e0 = 3.402823466e38f, e1 = 3.402823466e38f, e2 = 3.402823466e38f;
    int j0 = 0, j1 = 0, j2 = 0;

    for (int i0 = 0; i0 < 512; i0 += 8) {
        float4 pv[8];
        #pragma unroll
        for (int u = 0; u < 8; ++u) pv[u] = pb[i0 + u];   // scalar-load batch
        #pragma unroll
        for (int u = 0; u < 8; ++u) {
            float4 p = pv[u];   // (2x, 2y, 2z, sn)
            float dot2 = __fadd_rn(__fadd_rn(__fmul_rn(x, p.x), __fmul_rn(y, p.y)), __fmul_rn(z, p.z));
            float d    = __fsub_rn(__fadd_rn(sm, p.w), dot2);  // == ref bitwise
            bool lt2 = d < e2;
            if (__any(lt2)) {
                int n = nbase + i0 + u;
                bool lt0 = d < e0, lt1 = d < e1;
                // in-place, descending order: no temps, no movs
                j2 = lt2 ? (lt1 ? j1 : n) : j2;
                j1 = lt1 ? (lt0 ? j0 : n) : j1;
                j0 = lt0 ? n : j0;
                e2 = __builtin_amdgcn_fmed3f(d, e1, e2);
                e1 = __builtin_amdgcn_fmed3f(d, e0, e1);
                e0 = fminf(e0, d);
            }
        }
    }

    PD[q][ml][0] = e0; PD[q][ml][1] = e1; PD[q][ml][2] = e2;
    PI[q][ml][0] = j0; PI[q][ml][1] = j1; PI[q][ml][2] = j2;
    __syncthreads();

    if (t < 64) {
        float f0 = 3.402823466e38f, f1 = 3.402823466e38f, f2 = 3.402823466e38f;
        int i0 = 0, i1 = 0, i2 = 0;
        #pragma unroll
        for (int qq = 0; qq < 8; ++qq) {
            #pragma unroll
            for (int k = 0; k < 3; ++k) {
                float d = PD[qq][t][k];
                int   n = PI[qq][t][k];
                bool lt0 = d < f0, lt1 = d < f1, lt2 = d < f2;
                i2 = lt2 ? (lt1 ? i1 : n) : i2;
                i1 = lt1 ? (lt0 ? i0 : n) : i1;
                i0 = lt0 ? n : i0;
                f2 = __builtin_amdgcn_fmed3f(d, f1, f2);
                f1 = __builtin_amdgcn_fmed3f(d, f0, f1);
                f0 = fminf(f0, d);
            }
        }
        // clamp (ref: d2<0 -> 1e-7; also floors tiny positives, measure~zero)
        f0 = fmaxf(f0, 1e-7f); f1 = fmaxf(f1, 1e-7f); f2 = fmaxf(f2, 1e-7f);
        float iv0 = 1.0f / f0, iv1 = 1.0f / f1, iv2 = 1.0f / f2;
        float s = iv0 + iv1 + iv2;
        size_t wb = ((size_t)b * MM + m0 + t) * 3;
        topw[wb + 0] = iv0 / s; topw[wb + 1] = iv1 / s; topw[wb + 2] = iv2 / s;
        topi[wb + 0] = i0;      topi[wb + 1] = i1;      topi[wb + 2] = i2;
    }
}

// ---------------------------------------------------------------------------
// interp: out[b,o,m] = sum_k w[m,k] * featT[b, idx[m,k], o]
// block = 256 thr, 32 m per block; LDS bounce for gathered rows.
// ---------------------------------------------------------------------------
__global__ __launch_bounds__(256) void interp_kernel(
    const float* __restrict__ featT, const float* __restrict__ topw,
    const int* __restrict__ topi, float* __restrict__ out)
{
    __shared__ float G[32][388];   // [m][k*128+o], row stride 388 (4-mod-32 pad)
    __shared__ float Wl[32][4];

    int b  = blockIdx.y;
    int m0 = blockIdx.x * 32;
    int t  = threadIdx.x;

    if (t < 96) {
        int mm = t / 3, k = t - (t / 3) * 3;
        Wl[mm][k] = topw[((size_t)b * MM + m0 + mm) * 3 + k];
    }
    int lane = t & 31, r8 = t >> 5;
    #pragma unroll
    for (int pass = 0; pass < 12; ++pass) {
        int r  = pass * 8 + r8;          // 96 rows: (m,k)
        int mm = r / 3, k = r - (r / 3) * 3;
        int idx = topi[((size_t)b * MM + m0 + mm) * 3 + k];
        const float4 v = *(const float4*)&featT[((size_t)(b * NIN + idx)) * COUT + lane * 4];
        *(float4*)&G[mm][k * 128 + lane * 4] = v;
    }
    __syncthreads();

    int m  = t & 31;
    int obq = (t >> 5) * 16;
    float w0 = Wl[m][0], w1 = Wl[m][1], w2 = Wl[m][2];
    const float* Gm = &G[m][0];
    size_t outbase = ((size_t)b * COUT) * MM + m0 + m;
    #pragma unroll
    for (int oi = 0; oi < 16; ++oi) {
        int o = obq + oi;
        float v = w0 * Gm[o] + w1 * Gm[128 + o] + w2 * Gm[256 + o];
        out[outbase + (size_t)o * MM] = v;
    }
}

// ---------------------------------------------------------------------------
extern "C" void kernel_launch(void* const* d_in, const int* in_sizes, int n_in,
                              void* d_out, int out_size, void* d_ws, size_t ws_size,
                              hipStream_t stream)
{
    const float* rgb    = (const float*)d_in[0];
    const float* xyzin  = (const float*)d_in[1];
    const float* xyzout = (const float*)d_in[2];
    const float* w1  = (const float*)d_in[3];
    const float* b1  = (const float*)d_in[4];
    const float* g1  = (const float*)d_in[5];
    const float* be1 = (const float*)d_in[6];
    const float* rm1 = (const float*)d_in[7];
    const float* rv1 = (const float*)d_in[8];
    const float* w2  = (const float*)d_in[9];
    const float* b2  = (const float*)d_in[10];
    const float* g2  = (const float*)d_in[11];
    const float* be2 = (const float*)d_in[12];
    const float* rm2 = (const float*)d_in[13];
    const float* rv2 = (const float*)d_in[14];
    const float* w3  = (const float*)d_in[15];
    const float* b3  = (const float*)d_in[16];
    const float* g3  = (const float*)d_in[17];
    const float* be3 = (const float*)d_in[18];
    const float* rm3 = (const float*)d_in[19];
    const float* rv3 = (const float*)d_in[20];
    float* out = (float*)d_out;

    // workspace carve (floats)
    float* ws   = (float*)d_ws;
    float* WT1  = ws;                     // 32768
    float* WT2  = WT1 + 32768;            // 16384
    float* WT3  = WT2 + 16384;            // 16384
    float* st   = WT3 + 16384;            // 768
    float4* packed = (float4*)(st + 768); // 65536 floats
    float* featA = st + 768 + 65536;      // 2097152  (layer1 out)
    float* featB = featA + 2097152;       // 2097152  (featT: B x N x 128)
    float* topw  = featB + 2097152;       // 196608
    int*   topi  = (int*)(topw + 196608); // 196608

    prep_kernel<<<256, 256, 0, stream>>>(w1, w2, w3,
        b1, g1, be1, rm1, rv1,
        b2, g2, be2, rm2, rv2,
        b3, g3, be3, rm3, rv3,
        xyzin, WT1, WT2, WT3, st, packed);

    mlp_kernel<CIN, false><<<dim3(BB * (NIN / 32)), 256, 0, stream>>>(
        rgb, WT1, st + 0, st + 128, featA);

    mlp23_kernel<<<dim3(BB * (NIN / 32)), 256, 0, stream>>>(
        featA, WT2, WT3, st + 256, st + 384, st + 512, st + 640, featB);

    knn_kernel<<<dim3(MM / 64, BB), 512, 0, stream>>>(packed, xyzout, topw, topi);

    interp_kernel<<<dim3(MM / 32, BB), 256, 0, stream>>>(featB, topw, topi, out);
}

// Round 8
// 251.337 us; speedup vs baseline: 1.3840x; 1.0432x over previous
//
#include <hip/hip_runtime.h>
#include <hip/hip_bf16.h>
#include <cstdint>
#include <cstddef>

// Problem constants (match reference)
constexpr int BB   = 4;
constexpr int NIN  = 4096;
constexpr int MM   = 16384;
constexpr int CIN  = 256;
constexpr int COUT = 128;
constexpr float EPSBN = 1e-5f;

// ---------------------------------------------------------------------------
// prep: transpose weights (Cout,Cin)->(Cin,Cout), fold BN into (s,t),
//       pack xyzin into float4 (2x, 2y, 2z, x^2+y^2+z^2).
//       2x is exact (power-of-2 scale), so (x*2x' + y*2y') + z*2z' is
//       bit-identical to 2*((x*x' + y*y') + z*z') of the reference.
// ---------------------------------------------------------------------------
__global__ __launch_bounds__(256) void prep_kernel(
    const float* __restrict__ w1, const float* __restrict__ w2, const float* __restrict__ w3,
    const float* __restrict__ b1, const float* __restrict__ g1, const float* __restrict__ be1,
    const float* __restrict__ rm1, const float* __restrict__ rv1,
    const float* __restrict__ b2, const float* __restrict__ g2, const float* __restrict__ be2,
    const float* __restrict__ rm2, const float* __restrict__ rv2,
    const float* __restrict__ b3, const float* __restrict__ g3, const float* __restrict__ be3,
    const float* __restrict__ rm3, const float* __restrict__ rv3,
    const float* __restrict__ xyzin,
    float* __restrict__ WT1, float* __restrict__ WT2, float* __restrict__ WT3,
    float* __restrict__ st, float4* __restrict__ packed)
{
    int tid  = blockIdx.x * blockDim.x + threadIdx.x;
    int nthr = gridDim.x * blockDim.x;

    for (int i = tid; i < CIN * COUT; i += nthr)
        WT1[i] = w1[(i & 127) * CIN + (i >> 7)];
    for (int i = tid; i < COUT * COUT; i += nthr)
        WT2[i] = w2[(i & 127) * COUT + (i >> 7)];
    for (int i = tid; i < COUT * COUT; i += nthr)
        WT3[i] = w3[(i & 127) * COUT + (i >> 7)];

    for (int i = tid; i < 3 * COUT; i += nthr) {
        int l = i >> 7, o = i & 127;
        const float* bb = (l == 0) ? b1 : (l == 1) ? b2 : b3;
        const float* gg = (l == 0) ? g1 : (l == 1) ? g2 : g3;
        const float* be = (l == 0) ? be1 : (l == 1) ? be2 : be3;
        const float* rm = (l == 0) ? rm1 : (l == 1) ? rm2 : rm3;
        const float* rv = (l == 0) ? rv1 : (l == 1) ? rv2 : rv3;
        float s = gg[o] / sqrtf(rv[o] + EPSBN);
        st[l * 256 + o]       = s;
        st[l * 256 + 128 + o] = s * (bb[o] - rm[o]) + be[o];
    }

    for (int i = tid; i < BB * NIN; i += nthr) {
        float x = xyzin[i * 3 + 0], y = xyzin[i * 3 + 1], z = xyzin[i * 3 + 2];
        float sn = __fadd_rn(__fadd_rn(__fmul_rn(x, x), __fmul_rn(y, y)), __fmul_rn(z, z));
        packed[i] = make_float4(2.0f * x, 2.0f * y, 2.0f * z, sn);
    }
}

// ---------------------------------------------------------------------------
// mlp layer: out[b,o,n] = relu(s[o]*(sum_k W[o,k]*in[b,k,n]) + t[o])
// block = 256 thr, tile = 128 o x 32 n, thread = 4o x 4n, BK=32
// TOUT=true writes point-major (B,N,128)
// 20KB LDS -> up to 8 resident blocks/CU hide the barrier drains
// (the fused 52KB variant capped at 2 blocks/CU and regressed ~10us).
// ---------------------------------------------------------------------------
template <int CI, bool TOUT>
__global__ __launch_bounds__(256) void mlp_kernel(
    const float* __restrict__ in, const float* __restrict__ WT,
    const float* __restrict__ svec, const float* __restrict__ tvec,
    float* __restrict__ out)
{
    __shared__ float Xs[32][32];
    __shared__ float Ws[32][128];

    int blk = blockIdx.x;
    int b   = blk >> 7;              // NIN/32 = 128 tiles per batch
    int n0  = (blk & 127) * 32;
    int t   = threadIdx.x;
    int og  = t & 31;                // o = og*4 .. +3
    int ng  = t >> 5;                // n = n0 + ng*4 .. +3

    float acc[4][4] = {};
    const float* inb = in + (size_t)b * CI * NIN;

    for (int k0 = 0; k0 < CI; k0 += 32) {
        __syncthreads();
        {   // stage X tile: 32 k x 32 n, one float4 per thread (coalesced)
            int r = t >> 3, c = (t & 7) * 4;
            *(float4*)&Xs[r][c] = *(const float4*)&inb[(size_t)(k0 + r) * NIN + n0 + c];
        }
        #pragma unroll
        for (int r = 0; r < 4; ++r) {  // stage W tile: 32 k x 128 o, 4 float4/thread
            int e = (r * 256 + t) * 4;   // flat float index in tile
            *(float4*)&Ws[0][e] = *(const float4*)&WT[(size_t)k0 * 128 + e];
        }
        __syncthreads();
        #pragma unroll
        for (int kk = 0; kk < 32; ++kk) {
            float w[4], xv[4];
            *(float4*)w  = *(const float4*)&Ws[kk][og * 4];
            *(float4*)xv = *(const float4*)&Xs[kk][ng * 4];
            #pragma unroll
            for (int oi = 0; oi < 4; ++oi)
                #pragma unroll
                for (int j = 0; j < 4; ++j)
                    acc[oi][j] = fmaf(w[oi], xv[j], acc[oi][j]);
        }
    }

    // epilogue: BN fold + relu
    #pragma unroll
    for (int oi = 0; oi < 4; ++oi) {
        float s  = svec[og * 4 + oi];
        float tt = tvec[og * 4 + oi];
        #pragma unroll
        for (int j = 0; j < 4; ++j)
            acc[oi][j] = fmaxf(fmaf(s, acc[oi][j], tt), 0.0f);
    }

    if (TOUT) {
        #pragma unroll
        for (int j = 0; j < 4; ++j) {
            int n = n0 + ng * 4 + j;
            float4 v = make_float4(acc[0][j], acc[1][j], acc[2][j], acc[3][j]);
            *(float4*)&out[((size_t)(b * NIN + n)) * COUT + og * 4] = v;
        }
    } else {
        #pragma unroll
        for (int oi = 0; oi < 4; ++oi) {
            int o = og * 4 + oi;
            float4 v = make_float4(acc[oi][0], acc[oi][1], acc[oi][2], acc[oi][3]);
            *(float4*)&out[((size_t)b * COUT + o) * NIN + n0 + ng * 4] = v;
        }
    }
}

// ---------------------------------------------------------------------------
// knn: per (b,m) find 3 smallest d2 over n (stable like top_k), store
// normalized inverse-distance weights + indices.
// block = 512 thr = 64 m x 8 scan-chunks of 512.
// Inner loop: 7-op exact distance (x2-prefolded), 1 v_cmp, then a DIVERGENT
// if (d<e2): s_and_saveexec + s_cbranch_execz -- no bool materialization, no
// ballot round-trip; body runs exec-masked, skipped when no lane improves.
// Inside, d<e2 is implied by exec so j2 needs only one cndmask level.
// ---------------------------------------------------------------------------
__global__ __launch_bounds__(512) void knn_kernel(
    const float4* __restrict__ packed, const float* __restrict__ xyzout,
    float* __restrict__ topw, int* __restrict__ topi)
{
    __shared__ float PD[8][64][3];
    __shared__ int   PI[8][64][3];

    int b  = blockIdx.y;
    int m0 = blockIdx.x * 64;
    int t  = threadIdx.x;
    int ml = t & 63, q = t >> 6;
    int m  = m0 + ml;

    size_t ob = ((size_t)b * MM + m) * 3;
    float x = xyzout[ob], y = xyzout[ob + 1], z = xyzout[ob + 2];
    float sm = __fadd_rn(__fadd_rn(__fmul_rn(x, x), __fmul_rn(y, y)), __fmul_rn(z, z));

    // q is wave-uniform (64-lane waves): force SGPR so packed[] scans are
    // scalar-cache loads (one s_load serves the whole wave).
    int qs = __builtin_amdgcn_readfirstlane(q);
    int nbase = qs * 512;
    const float4* pb = packed + (size_t)b * NIN + nbase;

    float e0 = 3.402823466e38f, e1 = 3.402823466e38f, e2 = 3.402823466e38f;
    int j0 = 0, j1 = 0, j2 = 0;

    for (int i0 = 0; i0 < 512; i0 += 8) {
        float4 pv[8];
        #pragma unroll
        for (int u = 0; u < 8; ++u) pv[u] = pb[i0 + u];   // scalar-load batch
        #pragma unroll
        for (int u = 0; u < 8; ++u) {
            float4 p = pv[u];   // (2x, 2y, 2z, sn)
            float dot2 = __fadd_rn(__fadd_rn(__fmul_rn(x, p.x), __fmul_rn(y, p.y)), __fmul_rn(z, p.z));
            float d    = __fsub_rn(__fadd_rn(sm, p.w), dot2);  // == ref bitwise
            if (d < e2) {   // divergent: exec-masked insert, branch skips when vccz
                int n = nbase + i0 + u;
                bool lt0 = d < e0, lt1 = d < e1;
                j2 = lt1 ? j1 : n;          // d<e2 implied by exec
                j1 = lt1 ? (lt0 ? j0 : n) : j1;
                j0 = lt0 ? n : j0;
                e2 = __builtin_amdgcn_fmed3f(d, e1, e2);
                e1 = __builtin_amdgcn_fmed3f(d, e0, e1);
                e0 = fminf(e0, d);
            }
        }
    }

    PD[q][ml][0] = e0; PD[q][ml][1] = e1; PD[q][ml][2] = e2;
    PI[q][ml][0] = j0; PI[q][ml][1] = j1; PI[q][ml][2] = j2;
    __syncthreads();

    if (t < 64) {
        float f0 = 3.402823466e38f, f1 = 3.402823466e38f, f2 = 3.402823466e38f;
        int i0 = 0, i1 = 0, i2 = 0;
        #pragma unroll
        for (int qq = 0; qq < 8; ++qq) {
            #pragma unroll
            for (int k = 0; k < 3; ++k) {
                float d = PD[qq][t][k];
                int   n = PI[qq][t][k];
                bool lt0 = d < f0, lt1 = d < f1, lt2 = d < f2;
                i2 = lt2 ? (lt1 ? i1 : n) : i2;
                i1 = lt1 ? (lt0 ? i0 : n) : i1;
                i0 = lt0 ? n : i0;
                f2 = __builtin_amdgcn_fmed3f(d, f1, f2);
                f1 = __builtin_amdgcn_fmed3f(d, f0, f1);
                f0 = fminf(f0, d);
            }
        }
        // clamp (ref: d2<0 -> 1e-7; also floors tiny positives, measure~zero)
        f0 = fmaxf(f0, 1e-7f); f1 = fmaxf(f1, 1e-7f); f2 = fmaxf(f2, 1e-7f);
        float iv0 = 1.0f / f0, iv1 = 1.0f / f1, iv2 = 1.0f / f2;
        float s = iv0 + iv1 + iv2;
        size_t wb = ((size_t)b * MM + m0 + t) * 3;
        topw[wb + 0] = iv0 / s; topw[wb + 1] = iv1 / s; topw[wb + 2] = iv2 / s;
        topi[wb + 0] = i0;      topi[wb + 1] = i1;      topi[wb + 2] = i2;
    }
}

// ---------------------------------------------------------------------------
// interp: out[b,o,m] = sum_k w[m,k] * featT[b, idx[m,k], o]
// block = 256 thr, 32 m per block; LDS bounce for gathered rows.
// ---------------------------------------------------------------------------
__global__ __launch_bounds__(256) void interp_kernel(
    const float* __restrict__ featT, const float* __restrict__ topw,
    const int* __restrict__ topi, float* __restrict__ out)
{
    __shared__ float G[32][388];   // [m][k*128+o], row stride 388 (4-mod-32 pad)
    __shared__ float Wl[32][4];

    int b  = blockIdx.y;
    int m0 = blockIdx.x * 32;
    int t  = threadIdx.x;

    if (t < 96) {
        int mm = t / 3, k = t - (t / 3) * 3;
        Wl[mm][k] = topw[((size_t)b * MM + m0 + mm) * 3 + k];
    }
    int lane = t & 31, r8 = t >> 5;
    #pragma unroll
    for (int pass = 0; pass < 12; ++pass) {
        int r  = pass * 8 + r8;          // 96 rows: (m,k)
        int mm = r / 3, k = r - (r / 3) * 3;
        int idx = topi[((size_t)b * MM + m0 + mm) * 3 + k];
        const float4 v = *(const float4*)&featT[((size_t)(b * NIN + idx)) * COUT + lane * 4];
        *(float4*)&G[mm][k * 128 + lane * 4] = v;
    }
    __syncthreads();

    int m  = t & 31;
    int obq = (t >> 5) * 16;
    float w0 = Wl[m][0], w1 = Wl[m][1], w2 = Wl[m][2];
    const float* Gm = &G[m][0];
    size_t outbase = ((size_t)b * COUT) * MM + m0 + m;
    #pragma unroll
    for (int oi = 0; oi < 16; ++oi) {
        int o = obq + oi;
        float v = w0 * Gm[o] + w1 * Gm[128 + o] + w2 * Gm[256 + o];
        out[outbase + (size_t)o * MM] = v;
    }
}

// ---------------------------------------------------------------------------
extern "C" void kernel_launch(void* const* d_in, const int* in_sizes, int n_in,
                              void* d_out, int out_size, void* d_ws, size_t ws_size,
                              hipStream_t stream)
{
    const float* rgb    = (const float*)d_in[0];
    const float* xyzin  = (const float*)d_in[1];
    const float* xyzout = (const float*)d_in[2];
    const float* w1  = (const float*)d_in[3];
    const float* b1  = (const float*)d_in[4];
    const float* g1  = (const float*)d_in[5];
    const float* be1 = (const float*)d_in[6];
    const float* rm1 = (const float*)d_in[7];
    const float* rv1 = (const float*)d_in[8];
    const float* w2  = (const float*)d_in[9];
    const float* b2  = (const float*)d_in[10];
    const float* g2  = (const float*)d_in[11];
    const float* be2 = (const float*)d_in[12];
    const float* rm2 = (const float*)d_in[13];
    const float* rv2 = (const float*)d_in[14];
    const float* w3  = (const float*)d_in[15];
    const float* b3  = (const float*)d_in[16];
    const float* g3  = (const float*)d_in[17];
    const float* be3 = (const float*)d_in[18];
    const float* rm3 = (const float*)d_in[19];
    const float* rv3 = (const float*)d_in[20];
    float* out = (float*)d_out;

    // workspace carve (floats)
    float* ws   = (float*)d_ws;
    float* WT1  = ws;                     // 32768
    float* WT2  = WT1 + 32768;            // 16384
    float* WT3  = WT2 + 16384;            // 16384
    float* st   = WT3 + 16384;            // 768
    float4* packed = (float4*)(st + 768); // 65536 floats
    float* featA = st + 768 + 65536;      // 2097152  (layer1 out, later featT)
    float* featB = featA + 2097152;       // 2097152  (layer2 out)
    float* topw  = featB + 2097152;       // 196608
    int*   topi  = (int*)(topw + 196608); // 196608

    prep_kernel<<<256, 256, 0, stream>>>(w1, w2, w3,
        b1, g1, be1, rm1, rv1,
        b2, g2, be2, rm2, rv2,
        b3, g3, be3, rm3, rv3,
        xyzin, WT1, WT2, WT3, st, packed);

    mlp_kernel<CIN, false><<<dim3(BB * (NIN / 32)), 256, 0, stream>>>(
        rgb, WT1, st + 0, st + 128, featA);
    mlp_kernel<COUT, false><<<dim3(BB * (NIN / 32)), 256, 0, stream>>>(
        featA, WT2, st + 256, st + 384, featB);
    mlp_kernel<COUT, true><<<dim3(BB * (NIN / 32)), 256, 0, stream>>>(
        featB, WT3, st + 512, st + 640, featA);   // featA now = featT (B,N,128)

    knn_kernel<<<dim3(MM / 64, BB), 512, 0, stream>>>(packed, xyzout, topw, topi);

    interp_kernel<<<dim3(MM / 32, BB), 256, 0, stream>>>(featA, topw, topi, out);
}